// Round 3
// baseline (199.329 us; speedup 1.0000x reference)
//
#include <hip/hip_runtime.h>

// TriangleLinear: out[b][8191-r] = bias[r] + sum_{c>=max(0,r-4)} W_packed[...] * x[b][c]
// HBM-bound on the 134.4 MB packed-weight stream (read once) => ~21 us kernel floor.
// Graded dur includes ~157 us of harness d_ws poison-fills (2 x 537 MB @ 78 us) we
// don't control; kernel residual ~40 us in R2.
// R2 post-mortem: weight loads were 16 scalar NT dwords/thread, 16 B lane stride ->
// 4 B used per 16 B fetched per instr, NT defeats line reuse -> ~2x HBM over-fetch.
// R3: one unaligned float4 per (row,thread) weight load (gfx950 handles align-4
// dwordx4), no NT. 4x fewer weight VMEM instrs, full line utilization.

constexpr int N = 8192;      // N_IN == N_OUT
constexpr int BATCH = 8;
constexpr int ROWS = 4;      // rows per block: x loads shared across rows in registers
constexpr int THREADS = 256;
constexpr int VEC = 4;       // columns per thread (float4 loads)
constexpr int TILE = THREADS * VEC;  // 1024 columns per block-iteration

// Unaligned-tolerant 4-float vector: row bases w+off(r)-c0(r) are only 4 B aligned.
typedef float f32x4v __attribute__((ext_vector_type(4)));
typedef f32x4v __attribute__((aligned(4))) f32x4u;

__global__ __launch_bounds__(THREADS, 4)
void tri_linear_kernel(const float* __restrict__ x,
                       const float* __restrict__ w,
                       const float* __restrict__ bias,
                       float* __restrict__ out) {
  const int t = threadIdx.x;
  const int r0 = blockIdx.x * ROWS;

  // Per-row triangular start column and packed-row base pointers (uniform -> SGPR).
  int c0[ROWS];
  const float* wrow[ROWS];
#pragma unroll
  for (int i = 0; i < ROWS; ++i) {
    const int r = r0 + i;
    c0[i] = (r > 4) ? (r - 4) : 0;
    // off(r) = 8192*r - (r-5)(r-4)/2 for r>=5, else 8192*r. (off(8192)=33,591,286 = nW)
    long long off = (r <= 5)
        ? (long long)r * N
        : (long long)r * N - ((long long)(r - 5) * (long long)(r - 4)) / 2;
    wrow[i] = w + (off - (long long)c0[i]);   // wrow[i][c] valid for c in [c0[i], N)
  }
  const int cbA = c0[0] & ~(TILE - 1);        // c0[0] == min c0 of this block's rows

  float acc[ROWS][BATCH];
#pragma unroll
  for (int i = 0; i < ROWS; ++i)
#pragma unroll
    for (int b = 0; b < BATCH; ++b) acc[i][b] = 0.0f;

  // ---- Edge tile [cbA, cbA+TILE): predicated on the triangular boundary ----
  {
    const int c = cbA + VEC * t;
    float4 xv[BATCH];
#pragma unroll
    for (int b = 0; b < BATCH; ++b)
      xv[b] = *(const float4*)(x + b * N + c);
#pragma unroll
    for (int i = 0; i < ROWS; ++i) {
#pragma unroll
      for (int j = 0; j < VEC; ++j) {
        const int cj = c + j;
        const float wv = (cj >= c0[i]) ? wrow[i][cj] : 0.0f;
#pragma unroll
        for (int b = 0; b < BATCH; ++b) {
          const float* xe = reinterpret_cast<const float*>(&xv[b]);
          acc[i][b] = fmaf(wv, xe[j], acc[i][b]);
        }
      }
    }
  }

  // ---- Main loop: predicate-free, float4 everywhere ----
  for (int cb = cbA + TILE; cb < N; cb += TILE) {
    const int c = cb + VEC * t;
    f32x4v wv[ROWS];
#pragma unroll
    for (int i = 0; i < ROWS; ++i)
      wv[i] = *(const f32x4u*)(wrow[i] + c);   // unaligned dwordx4, full-line use
    float4 xv[BATCH];
#pragma unroll
    for (int b = 0; b < BATCH; ++b)
      xv[b] = *(const float4*)(x + b * N + c); // 16 B aligned, L2-hot
#pragma unroll
    for (int i = 0; i < ROWS; ++i)
#pragma unroll
      for (int j = 0; j < VEC; ++j) {
#pragma unroll
        for (int b = 0; b < BATCH; ++b) {
          const float* xe = reinterpret_cast<const float*>(&xv[b]);
          acc[i][b] = fmaf(wv[i][j], xe[j], acc[i][b]);
        }
      }
  }

  // ---- Reduction: 32 (row,batch) sums over 256 threads, transposed LDS tile ----
  // red[256][33] = 33.8 KB -> 4 blocks/CU with the 1.2 KB second stage.
  __shared__ float red[THREADS][ROWS * BATCH + 1];
#pragma unroll
  for (int i = 0; i < ROWS; ++i)
#pragma unroll
    for (int b = 0; b < BATCH; ++b)
      red[t][i * BATCH + b] = acc[i][b];
  __syncthreads();

  const int s = t & 31;     // which (row,batch) sum
  const int part = t >> 5;  // which 32-thread chunk
  float p = 0.0f;
#pragma unroll
  for (int k = 0; k < 32; ++k) p += red[part * 32 + k][s];

  __shared__ float red2[32][9];
  red2[s][part] = p;
  __syncthreads();

  if (t < 32) {
    float total = 0.0f;
#pragma unroll
    for (int g = 0; g < 8; ++g) total += red2[t][g];
    const int i = t >> 3, b = t & 7;   // t == i*BATCH + b == s
    const int r = r0 + i;
    out[b * N + (N - 1 - r)] = total + bias[r];  // last-dim flip + bias
  }
}

extern "C" void kernel_launch(void* const* d_in, const int* in_sizes, int n_in,
                              void* d_out, int out_size, void* d_ws, size_t ws_size,
                              hipStream_t stream) {
  const float* x    = (const float*)d_in[0];  // [8, 8192]
  const float* w    = (const float*)d_in[1];  // [33591286] packed triangular
  const float* bias = (const float*)d_in[2];  // [8192]
  float* out = (float*)d_out;                 // [8, 8192]
  tri_linear_kernel<<<N / ROWS, THREADS, 0, stream>>>(x, w, bias, out);
}